// Round 1
// baseline (95.593 us; speedup 1.0000x reference)
//
#include <hip/hip_runtime.h>

// Chamfer distance, B=4, N=M=8192, f32 in/out.
// out = [dist1 (B*N floats) | dist2 (B*M floats)]   (65536 floats total)
//
// d(q,r) = |q|^2 + |r|^2 - 2 q.r  (same expansion as the reference).
// Per query we compute min_j (rsq_j - 2 q.r_j) and add qsq at the end
// (constant shift commutes with min), then clamp at 0 (max(min,0) == min(max,0)).
// Pre-scaling q by -2 makes the inner loop exactly 3 FMA + amortized min per pair.

#define TPB   256
#define QPT   8                    // queries per thread
#define QPB   (TPB * QPT)          // 2048 queries per block
#define SEG   16                   // splits of the reference dim
#define NPTS  8192
#define NB    4
#define RTILE (NPTS / SEG)         // 512 reference points per block

__global__ void chamfer_init_out(unsigned int* __restrict__ out, int n) {
    int i = blockIdx.x * blockDim.x + threadIdx.x;
    if (i < n) out[i] = 0x7F800000u;  // +inf bits
}

__global__ __launch_bounds__(TPB, 2) void chamfer_kernel(
    const float* __restrict__ xyz1,
    const float* __restrict__ xyz2,
    unsigned int* __restrict__ out)
{
    __shared__ float4 tile[RTILE];   // (rx, ry, rz, rsq) — 8 KiB

    int bid = blockIdx.x;
    int s   = bid & (SEG - 1); bid >>= 4;   // reference segment
    int qt  = bid & 3;         bid >>= 2;   // query tile (N/QPB == 4)
    int b   = bid & 3;         bid >>= 2;   // batch
    int dir = bid;                          // 0: dist1 (q=xyz1,r=xyz2), 1: dist2

    const float* qptr = dir ? xyz2 : xyz1;
    const float* rptr = dir ? xyz1 : xyz2;
    const int outbase = dir * (NB * NPTS) + b * NPTS;

    // Stage reference tile into LDS with precomputed |r|^2.
    for (int j = threadIdx.x; j < RTILE; j += TPB) {
        int g = (b * NPTS + s * RTILE + j) * 3;
        float x = rptr[g], y = rptr[g + 1], z = rptr[g + 2];
        tile[j] = make_float4(x, y, z, x * x + y * y + z * z);
    }

    // Load this thread's 8 query points into registers (pre-scaled by -2).
    float qx2[QPT], qy2[QPT], qz2[QPT], qs[QPT], m[QPT];
#pragma unroll
    for (int k = 0; k < QPT; ++k) {
        int q = qt * QPB + k * TPB + threadIdx.x;
        int g = (b * NPTS + q) * 3;
        float x = qptr[g], y = qptr[g + 1], z = qptr[g + 2];
        qx2[k] = -2.0f * x;
        qy2[k] = -2.0f * y;
        qz2[k] = -2.0f * z;
        qs[k]  = x * x + y * y + z * z;
        m[k]   = INFINITY;
    }
    __syncthreads();

    // Main loop: 4 reference points per iteration, broadcast LDS reads.
    for (int j = 0; j < RTILE; j += 4) {
        float4 r0 = tile[j + 0];
        float4 r1 = tile[j + 1];
        float4 r2 = tile[j + 2];
        float4 r3 = tile[j + 3];
#pragma unroll
        for (int k = 0; k < QPT; ++k) {
            float d0 = fmaf(qz2[k], r0.z, fmaf(qy2[k], r0.y, fmaf(qx2[k], r0.x, r0.w)));
            float d1 = fmaf(qz2[k], r1.z, fmaf(qy2[k], r1.y, fmaf(qx2[k], r1.x, r1.w)));
            float d2 = fmaf(qz2[k], r2.z, fmaf(qy2[k], r2.y, fmaf(qx2[k], r2.x, r2.w)));
            float d3 = fmaf(qz2[k], r3.z, fmaf(qy2[k], r3.y, fmaf(qx2[k], r3.x, r3.w)));
            // min tree -> v_min3_f32 fusion
            m[k] = fminf(m[k], fminf(fminf(d0, d1), fminf(d2, d3)));
        }
    }

    // Fold qsq back in, clamp, publish partial min via uint atomicMin
    // (all values >= 0 so float bits are monotone).
#pragma unroll
    for (int k = 0; k < QPT; ++k) {
        int q = qt * QPB + k * TPB + threadIdx.x;
        float d = fmaxf(qs[k] + m[k], 0.0f);
        atomicMin(&out[outbase + q], __float_as_uint(d));
    }
}

extern "C" void kernel_launch(void* const* d_in, const int* in_sizes, int n_in,
                              void* d_out, int out_size, void* d_ws, size_t ws_size,
                              hipStream_t stream) {
    const float* xyz1 = (const float*)d_in[0];
    const float* xyz2 = (const float*)d_in[1];
    unsigned int* out = (unsigned int*)d_out;

    // Init outputs to +inf (harness poisons d_out before every launch).
    hipLaunchKernelGGL(chamfer_init_out,
                       dim3((out_size + TPB - 1) / TPB), dim3(TPB), 0, stream,
                       out, out_size);

    // 2 dirs x 4 batches x 4 query tiles x 16 ref segments = 512 blocks.
    hipLaunchKernelGGL(chamfer_kernel,
                       dim3(2 * NB * (NPTS / QPB) * SEG), dim3(TPB), 0, stream,
                       xyz1, xyz2, out);
}

// Round 2
// 94.983 us; speedup vs baseline: 1.0064x; 1.0064x over previous
//
#include <hip/hip_runtime.h>

// Chamfer distance, B=4, N=M=8192, f32 in/out.
// out = [dist1 (B*N floats) | dist2 (B*M floats)]
//
// d(q,r) = |q|^2 + |r|^2 - 2 q.r. Per query: min_j (rsq_j - 2 q.r_j), add
// |q|^2 after the min, clamp at 0. Inner loop uses v_pk_fma_f32 (packed FP32,
// 2 reference points per instruction) + v_min3_f32:
//   per 4 pairs: 6 pk_fma + 2 min3  ->  ~2.1 VALU inst/pair incl. LDS reads.

typedef float f32x2 __attribute__((ext_vector_type(2)));

#define TPB    256
#define QPT    8                    // queries per thread
#define QPB    (TPB * QPT)          // 2048 queries per block
#define SEG    32                   // splits of the reference dim
#define NPTS   8192
#define NB     4
#define RTILE  (NPTS / SEG)         // 256 reference points per block
#define RPAIRS (RTILE / 2)          // 128 packed ref pairs

__device__ __forceinline__ f32x2 pk_fma(f32x2 a, f32x2 b, f32x2 c) {
    f32x2 d;
    asm("v_pk_fma_f32 %0, %1, %2, %3" : "=v"(d) : "v"(a), "v"(b), "v"(c));
    return d;
}

__device__ __forceinline__ float min3f(float a, float b, float c) {
    float d;
    asm("v_min3_f32 %0, %1, %2, %3" : "=v"(d) : "v"(a), "v"(b), "v"(c));
    return d;
}

__global__ void chamfer_init_out(unsigned int* __restrict__ out, int n) {
    int i = blockIdx.x * blockDim.x + threadIdx.x;
    if (i < n) out[i] = 0x7F800000u;  // +inf bits
}

__global__ __launch_bounds__(TPB, 4) void chamfer_kernel(
    const float* __restrict__ xyz1,
    const float* __restrict__ xyz2,
    unsigned int* __restrict__ out)
{
    // tile[2p]   = {x_2p, x_2p+1, y_2p, y_2p+1}
    // tile[2p+1] = {z_2p, z_2p+1, w_2p, w_2p+1}   (w = |r|^2)
    __shared__ float4 tile[2 * RPAIRS];   // 4 KiB

    int bid = blockIdx.x;
    int s   = bid & (SEG - 1); bid >>= 5;   // reference segment
    int qt  = bid & 3;         bid >>= 2;   // query tile (N/QPB == 4)
    int b   = bid & 3;         bid >>= 2;   // batch
    int dir = bid;                          // 0: dist1, 1: dist2

    const float* qptr = dir ? xyz2 : xyz1;
    const float* rptr = dir ? xyz1 : xyz2;
    const int outbase = dir * (NB * NPTS) + b * NPTS;

    // Stage reference tile into LDS, packed pairwise, with |r|^2.
    for (int p = threadIdx.x; p < RPAIRS; p += TPB) {
        int g = (b * NPTS + s * RTILE + 2 * p) * 3;
        float x0 = rptr[g + 0], y0 = rptr[g + 1], z0 = rptr[g + 2];
        float x1 = rptr[g + 3], y1 = rptr[g + 4], z1 = rptr[g + 5];
        tile[2 * p + 0] = make_float4(x0, x1, y0, y1);
        tile[2 * p + 1] = make_float4(z0, z1,
                                      x0 * x0 + y0 * y0 + z0 * z0,
                                      x1 * x1 + y1 * y1 + z1 * z1);
    }

    // This thread's 8 query points, pre-scaled by -2, broadcast into pairs.
    f32x2 qx[QPT], qy[QPT], qz[QPT];
    float qs[QPT], m[QPT];
#pragma unroll
    for (int k = 0; k < QPT; ++k) {
        int q = qt * QPB + k * TPB + threadIdx.x;
        int g = (b * NPTS + q) * 3;
        float x = qptr[g], y = qptr[g + 1], z = qptr[g + 2];
        qx[k].x = qx[k].y = -2.0f * x;
        qy[k].x = qy[k].y = -2.0f * y;
        qz[k].x = qz[k].y = -2.0f * z;
        qs[k] = x * x + y * y + z * z;
        m[k]  = INFINITY;
    }
    __syncthreads();

    // Main loop: 4 reference points (2 packed pairs) per iteration.
    for (int p = 0; p < 2 * RPAIRS; p += 4) {
        float4 u0 = tile[p + 0];
        float4 v0 = tile[p + 1];
        float4 u1 = tile[p + 2];
        float4 v1 = tile[p + 3];
        f32x2 x01; x01.x = u0.x; x01.y = u0.y;
        f32x2 y01; y01.x = u0.z; y01.y = u0.w;
        f32x2 z01; z01.x = v0.x; z01.y = v0.y;
        f32x2 w01; w01.x = v0.z; w01.y = v0.w;
        f32x2 x23; x23.x = u1.x; x23.y = u1.y;
        f32x2 y23; y23.x = u1.z; y23.y = u1.w;
        f32x2 z23; z23.x = v1.x; z23.y = v1.y;
        f32x2 w23; w23.x = v1.z; w23.y = v1.w;
#pragma unroll
        for (int k = 0; k < QPT; ++k) {
            f32x2 d01 = pk_fma(qz[k], z01, pk_fma(qy[k], y01, pk_fma(qx[k], x01, w01)));
            f32x2 d23 = pk_fma(qz[k], z23, pk_fma(qy[k], y23, pk_fma(qx[k], x23, w23)));
            m[k] = min3f(min3f(d01.x, d01.y, d23.x), d23.y, m[k]);
        }
    }

    // Fold |q|^2 back in, clamp, publish partial min via uint atomicMin
    // (all values >= 0 so float bits are monotone).
#pragma unroll
    for (int k = 0; k < QPT; ++k) {
        int q = qt * QPB + k * TPB + threadIdx.x;
        float d = fmaxf(qs[k] + m[k], 0.0f);
        atomicMin(&out[outbase + q], __float_as_uint(d));
    }
}

extern "C" void kernel_launch(void* const* d_in, const int* in_sizes, int n_in,
                              void* d_out, int out_size, void* d_ws, size_t ws_size,
                              hipStream_t stream) {
    const float* xyz1 = (const float*)d_in[0];
    const float* xyz2 = (const float*)d_in[1];
    unsigned int* out = (unsigned int*)d_out;

    hipLaunchKernelGGL(chamfer_init_out,
                       dim3((out_size + TPB - 1) / TPB), dim3(TPB), 0, stream,
                       out, out_size);

    // 2 dirs x 4 batches x 4 query tiles x 32 ref segments = 1024 blocks.
    hipLaunchKernelGGL(chamfer_kernel,
                       dim3(2 * NB * (NPTS / QPB) * SEG), dim3(TPB), 0, stream,
                       xyz1, xyz2, out);
}

// Round 3
// 80.189 us; speedup vs baseline: 1.1921x; 1.1845x over previous
//
#include <hip/hip_runtime.h>

// Chamfer distance via bf16 MFMA with split-bf16 (hi+lo) distance packing.
// B=4, N=M=8192, f32 in/out. out = [dist1 (B*N) | dist2 (B*M)].
//
// d[i][j] = |q_i|^2 + |r_j|^2 - 2 q_i.r_j is computed ENTIRELY inside one
// v_mfma_f32_32x32x16_bf16 by packing K=16 slots:
//   k0-2 : (-2q)_hi * r_hi      k3-5 : (-2q)_lo * r_hi
//   k6-8 : (-2q)_hi * r_lo      k9-10: |q|^2 hi/lo * 1
//   k11-12: 1 * |r|^2 hi/lo     k13-15: 0
// (hi = bf16(v), lo = bf16(v - hi); dropped lo*lo term ~1e-4.)
// Epilogue is just a running min over acc regs; row-mins only — dist2 comes
// from a second direction with roles swapped (no cross-lane/col reduction).

typedef __bf16 bf16_t;
typedef __bf16 bf16x8 __attribute__((ext_vector_type(8)));
typedef float  f32x16 __attribute__((ext_vector_type(16)));

#define NPTS    8192
#define NB      4
#define NSETPTS (NB * NPTS)      // 32768 points per set
#define TPB     256
#define WAVES   4
#define QPW     2                // q-tiles (of 32 rows) per wave
#define QC      (WAVES * QPW * 32)  // 256 query rows per block
#define SEGR    4                // ref-dim split
#define RC      (NPTS / SEGR)    // 2048 refs per block sweep
#define RT      (RC / 32)        // 64 r-tiles per sweep

__global__ void chamfer_init_out(unsigned int* __restrict__ out, int n) {
    int i = blockIdx.x * blockDim.x + threadIdx.x;
    if (i < n) out[i] = 0x7F800000u;  // +inf
}

__device__ __forceinline__ void split2(float v, bf16_t& h, bf16_t& l) {
    h = (bf16_t)v;
    l = (bf16_t)(v - (float)h);
}

// Build per-point A-side and B-side K=16 slot vectors, stored permuted so a
// fragment load is a single 16B load per lane:
// stored[j] = logical[perm[j]], perm = {0,1,2,3, 8,9,10,11, 4,5,6,7, 12,13,14,15}
// (lane-half h reads stored[8h..8h+7] = logical k {4h..4h+3, 8+4h..8+4h+3},
//  matching the two K=8 sub-fragments of mfma_32x32x16.)
__global__ void chamfer_prep(const float* __restrict__ xyz1,
                             const float* __restrict__ xyz2,
                             bf16_t* __restrict__ a16,
                             bf16_t* __restrict__ b16) {
    int i = blockIdx.x * blockDim.x + threadIdx.x;   // 0..2*NSETPTS-1
    const float* src = (i >= NSETPTS) ? xyz2 : xyz1;
    int p = i & (NSETPTS - 1);
    float x = src[3 * p], y = src[3 * p + 1], z = src[3 * p + 2];
    float sq = x * x + y * y + z * z;

    bf16_t m2xh, m2xl, m2yh, m2yl, m2zh, m2zl;
    split2(-2.f * x, m2xh, m2xl);
    split2(-2.f * y, m2yh, m2yl);
    split2(-2.f * z, m2zh, m2zl);
    bf16_t xh, xl, yh, yl, zh, zl;
    split2(x, xh, xl); split2(y, yh, yl); split2(z, zh, zl);
    bf16_t sqh, sql;
    split2(sq, sqh, sql);
    bf16_t one = (bf16_t)1.0f, zero = (bf16_t)0.0f;

    bf16_t A[16]  = { m2xh, m2yh, m2zh,  m2xl, m2yl, m2zl,
                      m2xh, m2yh, m2zh,  sqh, sql, one, one, zero, zero, zero };
    bf16_t Bv[16] = { xh, yh, zh,  xh, yh, zh,  xl, yl, zl,
                      one, one, sqh, sql, zero, zero, zero };

    const int perm[16] = {0,1,2,3, 8,9,10,11, 4,5,6,7, 12,13,14,15};
    bf16_t* ao = a16 + (size_t)i * 16;
    bf16_t* bo = b16 + (size_t)i * 16;
#pragma unroll
    for (int j = 0; j < 16; ++j) { ao[j] = A[perm[j]]; bo[j] = Bv[perm[j]]; }
}

__global__ __launch_bounds__(TPB, 4) void chamfer_main(
    const bf16_t* __restrict__ a16,
    const bf16_t* __restrict__ b16,
    unsigned int* __restrict__ out)
{
    __shared__ float red[WAVES][QPW][32][33];   // +1 pad; ~33 KB

    int bid = blockIdx.x;
    int s   = bid & (SEGR - 1); bid >>= 2;
    int qp  = bid & 31;         bid >>= 5;   // 8192/QC = 32 q-panels
    int b   = bid & 3;          bid >>= 2;
    int dir = bid;                            // 0: q=xyz1,r=xyz2 ; 1: swapped

    int wave = threadIdx.x >> 6;
    int lane = threadIdx.x & 63;
    int col  = lane & 31;                     // A-row / B-col index
    int h    = lane >> 5;                     // k sub-group

    const bf16_t* ap = a16 + ((size_t)dir * NB + b) * NPTS * 16;
    const bf16_t* bp = b16 + ((size_t)(1 - dir) * NB + b) * NPTS * 16;

    int qbase = qp * QC + wave * (QPW * 32);
    const bf16x8* a0p = (const bf16x8*)(ap + (size_t)(qbase + col) * 16) + h;
    const bf16x8* a1p = (const bf16x8*)(ap + (size_t)(qbase + 32 + col) * 16) + h;
    bf16x8 af0 = *a0p;
    bf16x8 af1 = *a1p;

    int rbase = s * RC;
    const bf16x8* bptr = (const bf16x8*)(bp + (size_t)(rbase + col) * 16) + h;
    // per-r-tile stride: 32 points * 16 bf16 = 512 bf16 = 64 bf16x8

    f32x16 rm0, rm1, zacc;
#pragma unroll
    for (int g = 0; g < 16; ++g) { rm0[g] = INFINITY; rm1[g] = INFINITY; zacc[g] = 0.f; }

    bf16x8 bf = bptr[0];
#pragma unroll 2
    for (int t = 0; t < RT; ++t) {
        int tn = (t + 1 < RT) ? (t + 1) : t;      // guard tail over-read
        bf16x8 bnx = bptr[(size_t)tn * 64];
        f32x16 acc0 = __builtin_amdgcn_mfma_f32_32x32x16_bf16(af0, bf, zacc, 0, 0, 0);
        f32x16 acc1 = __builtin_amdgcn_mfma_f32_32x32x16_bf16(af1, bf, zacc, 0, 0, 0);
#pragma unroll
        for (int g = 0; g < 16; ++g) rm0[g] = fminf(rm0[g], acc0[g]);
#pragma unroll
        for (int g = 0; g < 16; ++g) rm1[g] = fminf(rm1[g], acc1[g]);
        bf = bnx;
    }

    // Scatter running row-mins to LDS: D row = (g&3) + 8*(g>>2) + 4*h.
#pragma unroll
    for (int g = 0; g < 16; ++g) {
        int row = (g & 3) + 8 * (g >> 2) + 4 * h;
        red[wave][0][row][col] = rm0[g];
        red[wave][1][row][col] = rm1[g];
    }
    __syncthreads();

    // One thread per block-row: reduce 32 col-slots, clamp, publish.
    {
        int w  = threadIdx.x >> 6;
        int rem = threadIdx.x & 63;
        int qt = rem >> 5;
        int r  = rem & 31;
        const float* rowp = &red[w][qt][r][0];
        float v0 = rowp[0], v1 = rowp[1], v2 = rowp[2], v3 = rowp[3];
#pragma unroll
        for (int c = 4; c < 32; c += 4) {
            v0 = fminf(v0, rowp[c + 0]);
            v1 = fminf(v1, rowp[c + 1]);
            v2 = fminf(v2, rowp[c + 2]);
            v3 = fminf(v3, rowp[c + 3]);
        }
        float v = fminf(fminf(v0, v1), fminf(v2, v3));
        v = fmaxf(v, 0.f);
        unsigned idx = (unsigned)(dir * NSETPTS + b * NPTS + qp * QC + threadIdx.x);
        atomicMin(&out[idx], __float_as_uint(v));
    }
}

extern "C" void kernel_launch(void* const* d_in, const int* in_sizes, int n_in,
                              void* d_out, int out_size, void* d_ws, size_t ws_size,
                              hipStream_t stream) {
    const float* xyz1 = (const float*)d_in[0];
    const float* xyz2 = (const float*)d_in[1];
    unsigned int* out = (unsigned int*)d_out;

    bf16_t* a16 = (bf16_t*)d_ws;                          // 2 MB
    bf16_t* b16 = a16 + (size_t)2 * NSETPTS * 16;         // +2 MB (needs 4 MB ws)

    hipLaunchKernelGGL(chamfer_init_out,
                       dim3((out_size + TPB - 1) / TPB), dim3(TPB), 0, stream,
                       out, out_size);

    hipLaunchKernelGGL(chamfer_prep,
                       dim3(2 * NSETPTS / TPB), dim3(TPB), 0, stream,
                       xyz1, xyz2, a16, b16);

    // 2 dirs x 4 batches x 32 q-panels x 4 ref-segments = 1024 blocks
    hipLaunchKernelGGL(chamfer_main,
                       dim3(2 * NB * (NPTS / QC) * SEGR), dim3(TPB), 0, stream,
                       a16, b16, out);
}

// Round 6
// 77.761 us; speedup vs baseline: 1.2293x; 1.0312x over previous
//
#include <hip/hip_runtime.h>

// Chamfer distance via bf16 MFMA with split-bf16 (hi+lo) distance packing.
// B=4, N=M=8192, f32 in/out. out = [dist1 (B*N) | dist2 (B*M)].
//
// d[i][j] = |q_i|^2 + |r_j|^2 - 2 q_i.r_j computed entirely inside
// v_mfma_f32_32x32x16_bf16 via K=16 slot packing (see chamfer_prep).
//
// R5 = the PASSING R2 kernel + one delta: the r-tile loop processes tiles in
// pairs and folds with nested fminf (compiler may fuse to v_min3_f32).
// The failing R3/R4 rounds' inline-asm min3 on MFMA outputs and fused
// out-init are both REVERTED (bisect: they are the only shared suspects).

typedef __bf16 bf16_t;
typedef __bf16 bf16x8 __attribute__((ext_vector_type(8)));
typedef float  f32x16 __attribute__((ext_vector_type(16)));

#define NPTS    8192
#define NB      4
#define NSETPTS (NB * NPTS)          // 32768 points per set
#define TPB     256
#define WAVES   4
#define QPW     2                    // q-tiles (of 32 rows) per wave
#define QC      (WAVES * QPW * 32)   // 256 query rows per block
#define SEGR    4                    // ref-dim split
#define RC      (NPTS / SEGR)        // 2048 refs per block sweep
#define RT      (RC / 32)            // 64 r-tiles per sweep

__global__ void chamfer_init_out(unsigned int* __restrict__ out, int n) {
    int i = blockIdx.x * blockDim.x + threadIdx.x;
    if (i < n) out[i] = 0x7F800000u;  // +inf bits
}

__device__ __forceinline__ void split2(float v, bf16_t& h, bf16_t& l) {
    h = (bf16_t)v;
    l = (bf16_t)(v - (float)h);
}

// Per-point K=16 slot vectors (A-side and B-side), stored pre-permuted so a
// lane's fragment load is one 16B load: stored[j] = logical[perm[j]],
// perm = {0,1,2,3, 8,9,10,11, 4,5,6,7, 12,13,14,15}.
// Slots: k0-2 (-2q)_hi*r_hi | k3-5 (-2q)_lo*r_hi | k6-8 (-2q)_hi*r_lo |
//        k9-10 |q|^2 hi/lo * 1 | k11-12 1 * |r|^2 hi/lo | k13-15 zero.
__global__ void chamfer_prep(const float* __restrict__ xyz1,
                             const float* __restrict__ xyz2,
                             bf16_t* __restrict__ a16,
                             bf16_t* __restrict__ b16) {
    int i = blockIdx.x * blockDim.x + threadIdx.x;   // 0..2*NSETPTS-1
    const float* src = (i >= NSETPTS) ? xyz2 : xyz1;
    int p = i & (NSETPTS - 1);
    float x = src[3 * p], y = src[3 * p + 1], z = src[3 * p + 2];
    float sq = x * x + y * y + z * z;

    bf16_t m2xh, m2xl, m2yh, m2yl, m2zh, m2zl;
    split2(-2.f * x, m2xh, m2xl);
    split2(-2.f * y, m2yh, m2yl);
    split2(-2.f * z, m2zh, m2zl);
    bf16_t xh, xl, yh, yl, zh, zl;
    split2(x, xh, xl); split2(y, yh, yl); split2(z, zh, zl);
    bf16_t sqh, sql;
    split2(sq, sqh, sql);
    bf16_t one = (bf16_t)1.0f, zero = (bf16_t)0.0f;

    bf16_t A[16]  = { m2xh, m2yh, m2zh,  m2xl, m2yl, m2zl,
                      m2xh, m2yh, m2zh,  sqh, sql, one, one, zero, zero, zero };
    bf16_t Bv[16] = { xh, yh, zh,  xh, yh, zh,  xl, yl, zl,
                      one, one, sqh, sql, zero, zero, zero };

    const int perm[16] = {0,1,2,3, 8,9,10,11, 4,5,6,7, 12,13,14,15};
    bf16_t* ao = a16 + (size_t)i * 16;
    bf16_t* bo = b16 + (size_t)i * 16;
#pragma unroll
    for (int j = 0; j < 16; ++j) { ao[j] = A[perm[j]]; bo[j] = Bv[perm[j]]; }
}

__global__ __launch_bounds__(TPB, 4) void chamfer_main(
    const bf16_t* __restrict__ a16,
    const bf16_t* __restrict__ b16,
    unsigned int* __restrict__ out)
{
    __shared__ float red[WAVES][QPW][32][33];   // ~33 KB (+1 pad)

    int bid = blockIdx.x;
    int s   = bid & (SEGR - 1); bid >>= 2;   // reference segment
    int qp  = bid & 31;         bid >>= 5;   // q-panel (NPTS/QC == 32)
    int b   = bid & 3;          bid >>= 2;   // batch
    int dir = bid;                           // 0: q=xyz1,r=xyz2 ; 1: swapped

    int wave = threadIdx.x >> 6;
    int lane = threadIdx.x & 63;
    int col  = lane & 31;                    // A-row / B-col index
    int h    = lane >> 5;                    // k sub-group

    const bf16_t* ap = a16 + ((size_t)dir * NB + b) * NPTS * 16;
    const bf16_t* bp = b16 + ((size_t)(1 - dir) * NB + b) * NPTS * 16;

    int qbase = qp * QC + wave * (QPW * 32);
    const bf16x8* a0p = (const bf16x8*)(ap + (size_t)(qbase + col) * 16) + h;
    const bf16x8* a1p = (const bf16x8*)(ap + (size_t)(qbase + 32 + col) * 16) + h;
    bf16x8 af0 = *a0p;
    bf16x8 af1 = *a1p;

    int rbase = s * RC;
    const bf16x8* bptr = (const bf16x8*)(bp + (size_t)(rbase + col) * 16) + h;
    // per-r-tile stride: 32 points * 16 bf16 = 64 bf16x8

    f32x16 rm0, rm1, zacc;
#pragma unroll
    for (int g = 0; g < 16; ++g) { rm0[g] = INFINITY; rm1[g] = INFINITY; zacc[g] = 0.f; }

    // Pair-processed tile loop, 2 tiles in flight (RT even).
    bf16x8 c0 = bptr[0];
    bf16x8 c1 = bptr[64];
    for (int t = 0; t < RT; t += 2) {
        int n0 = (t + 2 < RT) ? (t + 2) : t;       // tail: reload current (inert)
        int n1 = (t + 3 < RT) ? (t + 3) : (t + 1);
        bf16x8 p0 = bptr[(size_t)n0 * 64];
        bf16x8 p1 = bptr[(size_t)n1 * 64];

        f32x16 a0 = __builtin_amdgcn_mfma_f32_32x32x16_bf16(af0, c0, zacc, 0, 0, 0);
        f32x16 a1 = __builtin_amdgcn_mfma_f32_32x32x16_bf16(af0, c1, zacc, 0, 0, 0);
#pragma unroll
        for (int g = 0; g < 16; ++g)
            rm0[g] = fminf(fminf(a0[g], a1[g]), rm0[g]);   // min3-fusable

        f32x16 a2 = __builtin_amdgcn_mfma_f32_32x32x16_bf16(af1, c0, zacc, 0, 0, 0);
        f32x16 a3 = __builtin_amdgcn_mfma_f32_32x32x16_bf16(af1, c1, zacc, 0, 0, 0);
#pragma unroll
        for (int g = 0; g < 16; ++g)
            rm1[g] = fminf(fminf(a2[g], a3[g]), rm1[g]);

        c0 = p0;
        c1 = p1;
    }

    // Scatter running row-mins: D row = (g&3) + 8*(g>>2) + 4*h (verified layout).
#pragma unroll
    for (int g = 0; g < 16; ++g) {
        int row = (g & 3) + 8 * (g >> 2) + 4 * h;
        red[wave][0][row][col] = rm0[g];
        red[wave][1][row][col] = rm1[g];
    }
    __syncthreads();

    // One thread per block q-row: reduce 32 col-slots, clamp, publish.
    {
        int w   = threadIdx.x >> 6;
        int rem = threadIdx.x & 63;
        int qt  = rem >> 5;
        int r   = rem & 31;
        const float* rp = &red[w][qt][r][0];
        float v0 = rp[0], v1 = rp[1], v2 = rp[2], v3 = rp[3];
#pragma unroll
        for (int c = 4; c < 32; c += 4) {
            v0 = fminf(v0, rp[c + 0]);
            v1 = fminf(v1, rp[c + 1]);
            v2 = fminf(v2, rp[c + 2]);
            v3 = fminf(v3, rp[c + 3]);
        }
        float v = fmaxf(fminf(fminf(v0, v1), fminf(v2, v3)), 0.f);
        unsigned idx = (unsigned)(dir * NSETPTS + b * NPTS + qp * QC + threadIdx.x);
        atomicMin(&out[idx], __float_as_uint(v));
    }
}

extern "C" void kernel_launch(void* const* d_in, const int* in_sizes, int n_in,
                              void* d_out, int out_size, void* d_ws, size_t ws_size,
                              hipStream_t stream) {
    const float* xyz1 = (const float*)d_in[0];
    const float* xyz2 = (const float*)d_in[1];
    unsigned int* out = (unsigned int*)d_out;

    bf16_t* a16 = (bf16_t*)d_ws;                          // 2 MB
    bf16_t* b16 = a16 + (size_t)2 * NSETPTS * 16;         // +2 MB

    hipLaunchKernelGGL(chamfer_init_out,
                       dim3((out_size + TPB - 1) / TPB), dim3(TPB), 0, stream,
                       out, out_size);

    hipLaunchKernelGGL(chamfer_prep,
                       dim3(2 * NSETPTS / TPB), dim3(TPB), 0, stream,
                       xyz1, xyz2, a16, b16);

    // 2 dirs x 4 batches x 32 q-panels x 4 ref-segments = 1024 blocks
    hipLaunchKernelGGL(chamfer_main,
                       dim3(2 * NB * (NPTS / QC) * SEGR), dim3(TPB), 0, stream,
                       a16, b16, out);
}